// Round 3
// baseline (369.628 us; speedup 1.0000x reference)
//
#include <hip/hip_runtime.h>
#include <hip/hip_bf16.h>

typedef __bf16 bf16;
typedef __bf16 bf16x4 __attribute__((ext_vector_type(4)));
typedef __bf16 bf16x8 __attribute__((ext_vector_type(8)));
typedef float floatx4 __attribute__((ext_vector_type(4)));

#define MFMA_16x16x32(a, b, c) __builtin_amdgcn_mfma_f32_16x16x32_bf16((a), (b), (c), 0, 0, 0)
#define NEG_INF (-__builtin_inff())

// Problem constants (B=2, S=2048, D=1024, H=16, d=64)
#define CB 2
#define CS 2048
#define CD 1024
#define CH 16
#define CM (CB * CS)
// Q prescale: DIM^-0.5 * log2(e)  (softmax done in base-2 domain)
#define QSC (0.03125f * 1.44269504088896340736f)

// async global->LDS, 16B per lane; LDS dest = wave-uniform base + lane*16
__device__ __forceinline__ void async16(const bf16* g, bf16* l) {
    __builtin_amdgcn_global_load_lds(
        (const __attribute__((address_space(1))) void*)g,
        (__attribute__((address_space(3))) void*)l, 16, 0, 0);
}

// ---------------------------------------------------------------------------
// Prep: x fp32 -> bf16
// ---------------------------------------------------------------------------
__global__ __launch_bounds__(256) void conv_x(const float* __restrict__ x,
                                              bf16* __restrict__ xb) {
    size_t i = ((size_t)blockIdx.x * 256 + threadIdx.x) * 8;
    float4 a = *(const float4*)(x + i);
    float4 b = *(const float4*)(x + i + 4);
    bf16x8 v;
    v[0] = (bf16)a.x; v[1] = (bf16)a.y; v[2] = (bf16)a.z; v[3] = (bf16)a.w;
    v[4] = (bf16)b.x; v[5] = (bf16)b.y; v[6] = (bf16)b.z; v[7] = (bf16)b.w;
    *(bf16x8*)(xb + i) = v;
}

// ---------------------------------------------------------------------------
// Prep: W [K][N] fp32 -> Wt [N][K] bf16 (64x64 LDS tile transpose)
// grid: (N/64, K/64, 4)  — z selects which W
// ---------------------------------------------------------------------------
__global__ __launch_bounds__(256) void conv_wt(
    const float* __restrict__ W0, const float* __restrict__ W1,
    const float* __restrict__ W2, const float* __restrict__ W3,
    bf16* __restrict__ Wt) {
    __shared__ bf16 Ws[64 * 68];
    const float* W = blockIdx.z == 0 ? W0 : blockIdx.z == 1 ? W1
                   : blockIdx.z == 2 ? W2 : W3;
    bf16* out = Wt + (size_t)blockIdx.z * CD * CD;
    const int t = threadIdx.x;
    const int n0 = blockIdx.x * 64, k0 = blockIdx.y * 64;
    const int rr = t >> 4, c4 = (t & 15) * 4;
#pragma unroll
    for (int i = 0; i < 4; i++) {
        int r = rr + i * 16;
        float4 f = *(const float4*)(W + (size_t)(k0 + r) * CD + n0 + c4);
        bf16x4 v;
        v[0] = (bf16)f.x; v[1] = (bf16)f.y; v[2] = (bf16)f.z; v[3] = (bf16)f.w;
        *(bf16x4*)&Ws[r * 68 + c4] = v;
    }
    __syncthreads();
#pragma unroll
    for (int i = 0; i < 4; i++) {
        int n = rr + i * 16;
        bf16x4 v;
#pragma unroll
        for (int j = 0; j < 4; j++) v[j] = Ws[(c4 + j) * 68 + n];
        *(bf16x4*)(out + (size_t)(n0 + n) * CD + k0 + c4) = v;
    }
}

// ---------------------------------------------------------------------------
// Fused QKV GEMM (m97 structure): 128x128 tile, BK=32, global_load_lds x16B.
// which = blockIdx.x>>3: 0->Q (scaled by QSC, [bh][S][64]), 1->K ([bh][S][64]),
// 2->V (transposed store [bh][64][S], packed bf16x4 along tokens).
// ---------------------------------------------------------------------------
__global__ __launch_bounds__(256) void gemm_qkv(
    const bf16* __restrict__ A, const bf16* __restrict__ Bt,
    const float* __restrict__ bq, const float* __restrict__ bk,
    const float* __restrict__ bv,
    bf16* __restrict__ Qb, bf16* __restrict__ Kb, bf16* __restrict__ Vb) {
    __shared__ bf16 As[128 * 32];
    __shared__ bf16 Bs[128 * 32];
    const int t = threadIdx.x, w = t >> 6, lane = t & 63;
    const int quad = lane >> 4, l15 = lane & 15;
    const int which = blockIdx.x >> 3;
    const int bn = (blockIdx.x & 7) * 128, bm = blockIdx.y * 128;
    const bf16* Bw = Bt + (size_t)which * CD * CD;

    const bf16* ag = A + (size_t)(bm + w * 16 + (lane >> 2)) * CD + (lane & 3) * 8;
    const bf16* bg = Bw + (size_t)(bn + w * 16 + (lane >> 2)) * CD + (lane & 3) * 8;
    const int lo = w * 16 * 32;   // wave-uniform LDS chunk base

    const int wm = (w >> 1) * 64, wn = (w & 1) * 64;
    floatx4 acc[4][4] = {};

    for (int k0 = 0; k0 < CD; k0 += 32) {
        async16(ag + k0, &As[lo]);
        async16(ag + (size_t)64 * CD + k0, &As[lo + 64 * 32]);
        async16(bg + k0, &Bs[lo]);
        async16(bg + (size_t)64 * CD + k0, &Bs[lo + 64 * 32]);
        __syncthreads();
        bf16x8 af[4], bfr[4];
#pragma unroll
        for (int mt = 0; mt < 4; mt++)
            af[mt] = *(const bf16x8*)&As[(wm + mt * 16 + l15) * 32 + quad * 8];
#pragma unroll
        for (int nt = 0; nt < 4; nt++)
            bfr[nt] = *(const bf16x8*)&Bs[(wn + nt * 16 + l15) * 32 + quad * 8];
#pragma unroll
        for (int mt = 0; mt < 4; mt++)
#pragma unroll
            for (int nt = 0; nt < 4; nt++)
                acc[mt][nt] = MFMA_16x16x32(af[mt], bfr[nt], acc[mt][nt]);
        __syncthreads();
    }

    const float* bias = which == 0 ? bq : which == 1 ? bk : bv;
    bf16* out = which == 0 ? Qb : Kb;
#pragma unroll
    for (int mt = 0; mt < 4; mt++) {
#pragma unroll
        for (int nt = 0; nt < 4; nt++) {
            int token = bm + wm + mt * 16 + quad * 4;      // 4 consecutive tokens
            int col = bn + wn + nt * 16 + l15;             // feature
            int b = token >> 11, s = token & (CS - 1);
            int h = col >> 6, dd = col & 63;
            if (which == 2) {
                // V^T [bh][d][S]: 4 tokens contiguous -> packed 8B store
                bf16x4 pv;
#pragma unroll
                for (int r = 0; r < 4; r++) pv[r] = (bf16)(acc[mt][nt][r] + bias[col]);
                *(bf16x4*)&Vb[(((size_t)(b * CH + h)) * 64 + dd) * CS + s] = pv;
            } else {
#pragma unroll
                for (int r = 0; r < 4; r++) {
                    float v = acc[mt][nt][r] + bias[col];
                    if (which == 0) v *= QSC;
                    out[(((size_t)(b * CH + h)) * CS + s + r) * 64 + dd] = (bf16)v;
                }
            }
        }
    }
}

// ---------------------------------------------------------------------------
// O-projection GEMM: 64x128 tile, fp32 output. grid: (8, M/64).
// ---------------------------------------------------------------------------
__global__ __launch_bounds__(256) void gemm_o(
    const bf16* __restrict__ A, const bf16* __restrict__ Bt,
    const float* __restrict__ bias, float* __restrict__ out) {
    __shared__ bf16 As[64 * 32];
    __shared__ bf16 Bs[128 * 32];
    const int t = threadIdx.x, w = t >> 6, lane = t & 63;
    const int quad = lane >> 4, l15 = lane & 15;
    const int bn = blockIdx.x * 128, bm = blockIdx.y * 64;

    const bf16* ag = A + (size_t)(bm + w * 16 + (lane >> 2)) * CD + (lane & 3) * 8;
    const bf16* bg = Bt + (size_t)(bn + w * 16 + (lane >> 2)) * CD + (lane & 3) * 8;
    const int lo = w * 16 * 32;

    const int wm = (w >> 1) * 32, wn = (w & 1) * 64;
    floatx4 acc[2][4] = {};

    for (int k0 = 0; k0 < CD; k0 += 32) {
        async16(ag + k0, &As[lo]);
        async16(bg + k0, &Bs[lo]);
        async16(bg + (size_t)64 * CD + k0, &Bs[lo + 64 * 32]);
        __syncthreads();
        bf16x8 af[2], bfr[4];
#pragma unroll
        for (int mt = 0; mt < 2; mt++)
            af[mt] = *(const bf16x8*)&As[(wm + mt * 16 + l15) * 32 + quad * 8];
#pragma unroll
        for (int nt = 0; nt < 4; nt++)
            bfr[nt] = *(const bf16x8*)&Bs[(wn + nt * 16 + l15) * 32 + quad * 8];
#pragma unroll
        for (int mt = 0; mt < 2; mt++)
#pragma unroll
            for (int nt = 0; nt < 4; nt++)
                acc[mt][nt] = MFMA_16x16x32(af[mt], bfr[nt], acc[mt][nt]);
        __syncthreads();
    }

#pragma unroll
    for (int mt = 0; mt < 2; mt++)
#pragma unroll
        for (int nt = 0; nt < 4; nt++)
#pragma unroll
            for (int r = 0; r < 4; r++) {
                int row = bm + wm + mt * 16 + quad * 4 + r;
                int col = bn + wn + nt * 16 + l15;
                out[(size_t)row * CD + col] = acc[mt][nt][r] + bias[col];
            }
}

// ---------------------------------------------------------------------------
// Barrier-free flash attention. Q pre-scaled by QSC (softmax in exp2 domain).
// Q/K: bf16 [bh][S][64]. V: bf16 [bh][64][S] (pre-transposed).
// All MFMA fragments loaded DIRECTLY from global (L1/L2-resident); the only
// LDS use is the per-wave P C-layout->A-layout round-trip. No __syncthreads.
// Row sums come from an extra MFMA against an all-ones fragment.
// ---------------------------------------------------------------------------
__global__ __launch_bounds__(256) void attn_kernel(
    const bf16* __restrict__ Q, const bf16* __restrict__ Kg,
    const bf16* __restrict__ Vg, bf16* __restrict__ Ob) {
    __shared__ bf16 Ps[4][16 * 72];   // per-wave P tile [qrow][key]

    const int t = threadIdx.x;
    const int wave = t >> 6, lane = t & 63;
    const int quad = lane >> 4, l15 = lane & 15;
    const int qt = gridDim.x - 1 - blockIdx.x;   // big tiles first
    const int q0 = qt * 64;
    const int bh = blockIdx.y;
    const int myRow0 = q0 + wave * 16;

    // Q fragments (A-operand) straight from global
    const bf16* qsrc = Q + ((size_t)bh * CS + myRow0 + l15) * 64 + quad * 8;
    bf16x8 qf0 = *(const bf16x8*)qsrc;
    bf16x8 qf1 = *(const bf16x8*)(qsrc + 32);

    // per-lane fragment base pointers
    const bf16* kbase = Kg + ((size_t)bh * CS + l15) * 64 + quad * 8;
    const bf16* vbase = Vg + ((size_t)bh * 64 + l15) * CS + quad * 8;

    floatx4 o[4] = {};
    float m_r[4], l_r[4];
#pragma unroll
    for (int r = 0; r < 4; r++) { m_r[r] = NEG_INF; l_r[r] = 0.f; }

    bf16x8 ones;
#pragma unroll
    for (int j = 0; j < 8; j++) ones[j] = (bf16)1.0f;

    bf16* ps = Ps[wave];

    for (int kt = 0; kt <= qt; kt++) {
        const int ks0 = kt * 64;
        const bf16* kp = kbase + (size_t)ks0 * 64;
        const bf16* vp = vbase + ks0;
        // ---- K fragments: B[k=dim][n=key], 16 dense 64B lines per load
        bf16x8 kf[4][2], vf[4][2];
#pragma unroll
        for (int nt = 0; nt < 4; nt++) {
            kf[nt][0] = *(const bf16x8*)(kp + nt * 1024);
            kf[nt][1] = *(const bf16x8*)(kp + nt * 1024 + 32);
        }
        // ---- V^T fragments: B[k=key][n=dim] (latency hidden behind QK+softmax)
#pragma unroll
        for (int dt = 0; dt < 4; dt++) {
            vf[dt][0] = *(const bf16x8*)(vp + (size_t)dt * 16 * CS);
            vf[dt][1] = *(const bf16x8*)(vp + (size_t)dt * 16 * CS + 32);
        }
        // ---- QK^T
        floatx4 sc[4] = {};
#pragma unroll
        for (int nt = 0; nt < 4; nt++) {
            sc[nt] = MFMA_16x16x32(qf0, kf[nt][0], sc[nt]);
            sc[nt] = MFMA_16x16x32(qf1, kf[nt][1], sc[nt]);
        }
        // ---- causal mask (diagonal tile only)
        if (ks0 + 63 > myRow0) {
#pragma unroll
            for (int nt = 0; nt < 4; nt++)
#pragma unroll
                for (int r = 0; r < 4; r++) {
                    int qrow = myRow0 + quad * 4 + r;
                    int kcol = ks0 + nt * 16 + l15;
                    if (kcol > qrow) sc[nt][r] = NEG_INF;
                }
        }
        // ---- running max + alpha (base-2 domain)
        float alpha[4];
#pragma unroll
        for (int r = 0; r < 4; r++) {
            float v = fmaxf(fmaxf(sc[0][r], sc[1][r]), fmaxf(sc[2][r], sc[3][r]));
#pragma unroll
            for (int off = 1; off < 16; off <<= 1) v = fmaxf(v, __shfl_xor(v, off));
            float mn = fmaxf(m_r[r], v);
            alpha[r] = __builtin_amdgcn_exp2f(m_r[r] - mn);
            m_r[r] = mn;
        }
        // ---- exponentiate
#pragma unroll
        for (int nt = 0; nt < 4; nt++)
#pragma unroll
            for (int r = 0; r < 4; r++)
                sc[nt][r] = __builtin_amdgcn_exp2f(sc[nt][r] - m_r[r]);
        // ---- P: C-layout -> LDS -> A-layout (per-wave, no barrier)
#pragma unroll
        for (int nt = 0; nt < 4; nt++)
#pragma unroll
            for (int r = 0; r < 4; r++)
                ps[(quad * 4 + r) * 72 + nt * 16 + l15] = (bf16)sc[nt][r];
        bf16x8 pf0 = *(const bf16x8*)&ps[l15 * 72 + quad * 8];
        bf16x8 pf1 = *(const bf16x8*)&ps[l15 * 72 + 32 + quad * 8];
        // ---- row sums via MFMA against ones (replaces 16 shuffles)
        floatx4 sr = {};
        sr = MFMA_16x16x32(pf0, ones, sr);
        sr = MFMA_16x16x32(pf1, ones, sr);
        // ---- rescale o, update l, accumulate PV
#pragma unroll
        for (int dt = 0; dt < 4; dt++)
#pragma unroll
            for (int r = 0; r < 4; r++) o[dt][r] *= alpha[r];
#pragma unroll
        for (int r = 0; r < 4; r++) l_r[r] = l_r[r] * alpha[r] + sr[r];
#pragma unroll
        for (int dt = 0; dt < 4; dt++) {
            o[dt] = MFMA_16x16x32(pf0, vf[dt][0], o[dt]);
            o[dt] = MFMA_16x16x32(pf1, vf[dt][1], o[dt]);
        }
    }

    // ---- epilogue: normalize, store [B][S][H*64]
    const int b = bh >> 4, h = bh & 15;
    float rl[4];
#pragma unroll
    for (int r = 0; r < 4; r++) rl[r] = 1.f / l_r[r];
#pragma unroll
    for (int dt = 0; dt < 4; dt++)
#pragma unroll
        for (int r = 0; r < 4; r++) {
            int srow = q0 + wave * 16 + quad * 4 + r;
            int col = h * 64 + dt * 16 + l15;
            Ob[((size_t)b * CS + srow) * CD + col] = (bf16)(o[dt][r] * rl[r]);
        }
}

// ---------------------------------------------------------------------------
extern "C" void kernel_launch(void* const* d_in, const int* in_sizes, int n_in,
                              void* d_out, int out_size, void* d_ws, size_t ws_size,
                              hipStream_t stream) {
    const float* x  = (const float*)d_in[0];
    const float* Wq = (const float*)d_in[1];
    const float* bq = (const float*)d_in[2];
    const float* Wk = (const float*)d_in[3];
    const float* bk = (const float*)d_in[4];
    const float* Wv = (const float*)d_in[5];
    const float* bv = (const float*)d_in[6];
    const float* Wo = (const float*)d_in[7];
    const float* bo = (const float*)d_in[8];
    float* out = (float*)d_out;

    // workspace (bf16 elems): xb[4M] Wt[4*1M] Qb[4M] Kb[4M] Vb[4M] Ob[4M]
    bf16* xb = (bf16*)d_ws;
    bf16* Wt = xb + (size_t)CM * CD;
    bf16* Qb = Wt + (size_t)4 * CD * CD;
    bf16* Kb = Qb + (size_t)CB * CH * CS * 64;
    bf16* Vb = Kb + (size_t)CB * CH * CS * 64;
    bf16* Ob = Vb + (size_t)CB * CH * CS * 64;

    conv_x<<<(CM * CD) / (256 * 8), 256, 0, stream>>>(x, xb);
    conv_wt<<<dim3(CD / 64, CD / 64, 4), 256, 0, stream>>>(Wq, Wk, Wv, Wo, Wt);

    gemm_qkv<<<dim3(24, CM / 128), 256, 0, stream>>>(
        xb, Wt, bq, bk, bv, Qb, Kb, Vb);

    attn_kernel<<<dim3(CS / 64, CB * CH), 256, 0, stream>>>(Qb, Kb, Vb, Ob);

    gemm_o<<<dim3(8, CM / 64), 256, 0, stream>>>(
        Ob, Wt + (size_t)3 * CD * CD, bo, out);
}

// Round 4
// 229.310 us; speedup vs baseline: 1.6119x; 1.6119x over previous
//
#include <hip/hip_runtime.h>
#include <hip/hip_bf16.h>

typedef __bf16 bf16;
typedef __bf16 bf16x4 __attribute__((ext_vector_type(4)));
typedef __bf16 bf16x8 __attribute__((ext_vector_type(8)));
typedef float floatx4 __attribute__((ext_vector_type(4)));

#define MFMA_16x16x32(a, b, c) __builtin_amdgcn_mfma_f32_16x16x32_bf16((a), (b), (c), 0, 0, 0)
#define NEG_INF (-__builtin_inff())

// Problem constants (B=2, S=2048, D=1024, H=16, d=64)
#define CB 2
#define CS 2048
#define CD 1024
#define CH 16
#define CM (CB * CS)
// Q prescale: DIM^-0.5 * log2(e)  (softmax done in base-2 domain)
#define QSC (0.03125f * 1.44269504088896340736f)

// async global->LDS, 16B per lane; LDS dest = wave-uniform base + lane*16
__device__ __forceinline__ void async16(const bf16* g, bf16* l) {
    __builtin_amdgcn_global_load_lds(
        (const __attribute__((address_space(1))) void*)g,
        (__attribute__((address_space(3))) void*)l, 16, 0, 0);
}

// ---------------------------------------------------------------------------
// Prep: x fp32 -> bf16
// ---------------------------------------------------------------------------
__global__ __launch_bounds__(256) void conv_x(const float* __restrict__ x,
                                              bf16* __restrict__ xb) {
    size_t i = ((size_t)blockIdx.x * 256 + threadIdx.x) * 8;
    float4 a = *(const float4*)(x + i);
    float4 b = *(const float4*)(x + i + 4);
    bf16x8 v;
    v[0] = (bf16)a.x; v[1] = (bf16)a.y; v[2] = (bf16)a.z; v[3] = (bf16)a.w;
    v[4] = (bf16)b.x; v[5] = (bf16)b.y; v[6] = (bf16)b.z; v[7] = (bf16)b.w;
    *(bf16x8*)(xb + i) = v;
}

// ---------------------------------------------------------------------------
// Prep: W [K][N] fp32 -> Wt [N][K] bf16 (64x64 LDS tile transpose)
// grid: (N/64, K/64, 4)  — z selects which W
// ---------------------------------------------------------------------------
__global__ __launch_bounds__(256) void conv_wt(
    const float* __restrict__ W0, const float* __restrict__ W1,
    const float* __restrict__ W2, const float* __restrict__ W3,
    bf16* __restrict__ Wt) {
    __shared__ bf16 Ws[64 * 68];
    const float* W = blockIdx.z == 0 ? W0 : blockIdx.z == 1 ? W1
                   : blockIdx.z == 2 ? W2 : W3;
    bf16* out = Wt + (size_t)blockIdx.z * CD * CD;
    const int t = threadIdx.x;
    const int n0 = blockIdx.x * 64, k0 = blockIdx.y * 64;
    const int rr = t >> 4, c4 = (t & 15) * 4;
#pragma unroll
    for (int i = 0; i < 4; i++) {
        int r = rr + i * 16;
        float4 f = *(const float4*)(W + (size_t)(k0 + r) * CD + n0 + c4);
        bf16x4 v;
        v[0] = (bf16)f.x; v[1] = (bf16)f.y; v[2] = (bf16)f.z; v[3] = (bf16)f.w;
        *(bf16x4*)&Ws[r * 68 + c4] = v;
    }
    __syncthreads();
#pragma unroll
    for (int i = 0; i < 4; i++) {
        int n = rr + i * 16;
        bf16x4 v;
#pragma unroll
        for (int j = 0; j < 4; j++) v[j] = Ws[(c4 + j) * 68 + n];
        *(bf16x4*)(out + (size_t)(n0 + n) * CD + k0 + c4) = v;
    }
}

// ---------------------------------------------------------------------------
// Fused QKV GEMM (m97 structure): 128x128 tile, BK=32, global_load_lds x16B.
// which = blockIdx.x>>3: 0->Q (scaled by QSC, [bh][S][64]), 1->K ([bh][S][64]),
// 2->V (transposed store [bh][64][S], packed bf16x4 along tokens).
// ---------------------------------------------------------------------------
__global__ __launch_bounds__(256) void gemm_qkv(
    const bf16* __restrict__ A, const bf16* __restrict__ Bt,
    const float* __restrict__ bq, const float* __restrict__ bk,
    const float* __restrict__ bv,
    bf16* __restrict__ Qb, bf16* __restrict__ Kb, bf16* __restrict__ Vb) {
    __shared__ bf16 As[128 * 32];
    __shared__ bf16 Bs[128 * 32];
    const int t = threadIdx.x, w = t >> 6, lane = t & 63;
    const int quad = lane >> 4, l15 = lane & 15;
    const int which = blockIdx.x >> 3;
    const int bn = (blockIdx.x & 7) * 128, bm = blockIdx.y * 128;
    const bf16* Bw = Bt + (size_t)which * CD * CD;

    const bf16* ag = A + (size_t)(bm + w * 16 + (lane >> 2)) * CD + (lane & 3) * 8;
    const bf16* bg = Bw + (size_t)(bn + w * 16 + (lane >> 2)) * CD + (lane & 3) * 8;
    const int lo = w * 16 * 32;   // wave-uniform LDS chunk base

    const int wm = (w >> 1) * 64, wn = (w & 1) * 64;
    floatx4 acc[4][4] = {};

    for (int k0 = 0; k0 < CD; k0 += 32) {
        async16(ag + k0, &As[lo]);
        async16(ag + (size_t)64 * CD + k0, &As[lo + 64 * 32]);
        async16(bg + k0, &Bs[lo]);
        async16(bg + (size_t)64 * CD + k0, &Bs[lo + 64 * 32]);
        __syncthreads();
        bf16x8 af[4], bfr[4];
#pragma unroll
        for (int mt = 0; mt < 4; mt++)
            af[mt] = *(const bf16x8*)&As[(wm + mt * 16 + l15) * 32 + quad * 8];
#pragma unroll
        for (int nt = 0; nt < 4; nt++)
            bfr[nt] = *(const bf16x8*)&Bs[(wn + nt * 16 + l15) * 32 + quad * 8];
#pragma unroll
        for (int mt = 0; mt < 4; mt++)
#pragma unroll
            for (int nt = 0; nt < 4; nt++)
                acc[mt][nt] = MFMA_16x16x32(af[mt], bfr[nt], acc[mt][nt]);
        __syncthreads();
    }

    const float* bias = which == 0 ? bq : which == 1 ? bk : bv;
    bf16* out = which == 0 ? Qb : Kb;
#pragma unroll
    for (int mt = 0; mt < 4; mt++) {
#pragma unroll
        for (int nt = 0; nt < 4; nt++) {
            int token = bm + wm + mt * 16 + quad * 4;      // 4 consecutive tokens
            int col = bn + wn + nt * 16 + l15;             // feature
            int b = token >> 11, s = token & (CS - 1);
            int h = col >> 6, dd = col & 63;
            if (which == 2) {
                // V^T [bh][d][S]: 4 tokens contiguous -> packed 8B store
                bf16x4 pv;
#pragma unroll
                for (int r = 0; r < 4; r++) pv[r] = (bf16)(acc[mt][nt][r] + bias[col]);
                *(bf16x4*)&Vb[(((size_t)(b * CH + h)) * 64 + dd) * CS + s] = pv;
            } else {
#pragma unroll
                for (int r = 0; r < 4; r++) {
                    float v = acc[mt][nt][r] + bias[col];
                    if (which == 0) v *= QSC;
                    out[(((size_t)(b * CH + h)) * CS + s + r) * 64 + dd] = (bf16)v;
                }
            }
        }
    }
}

// ---------------------------------------------------------------------------
// O-projection GEMM: 64x128 tile, fp32 output. grid: (8, M/64).
// ---------------------------------------------------------------------------
__global__ __launch_bounds__(256) void gemm_o(
    const bf16* __restrict__ A, const bf16* __restrict__ Bt,
    const float* __restrict__ bias, float* __restrict__ out) {
    __shared__ bf16 As[64 * 32];
    __shared__ bf16 Bs[128 * 32];
    const int t = threadIdx.x, w = t >> 6, lane = t & 63;
    const int quad = lane >> 4, l15 = lane & 15;
    const int bn = blockIdx.x * 128, bm = blockIdx.y * 64;

    const bf16* ag = A + (size_t)(bm + w * 16 + (lane >> 2)) * CD + (lane & 3) * 8;
    const bf16* bg = Bt + (size_t)(bn + w * 16 + (lane >> 2)) * CD + (lane & 3) * 8;
    const int lo = w * 16 * 32;

    const int wm = (w >> 1) * 32, wn = (w & 1) * 64;
    floatx4 acc[2][4] = {};

    for (int k0 = 0; k0 < CD; k0 += 32) {
        async16(ag + k0, &As[lo]);
        async16(bg + k0, &Bs[lo]);
        async16(bg + (size_t)64 * CD + k0, &Bs[lo + 64 * 32]);
        __syncthreads();
        bf16x8 af[2], bfr[4];
#pragma unroll
        for (int mt = 0; mt < 2; mt++)
            af[mt] = *(const bf16x8*)&As[(wm + mt * 16 + l15) * 32 + quad * 8];
#pragma unroll
        for (int nt = 0; nt < 4; nt++)
            bfr[nt] = *(const bf16x8*)&Bs[(wn + nt * 16 + l15) * 32 + quad * 8];
#pragma unroll
        for (int mt = 0; mt < 2; mt++)
#pragma unroll
            for (int nt = 0; nt < 4; nt++)
                acc[mt][nt] = MFMA_16x16x32(af[mt], bfr[nt], acc[mt][nt]);
        __syncthreads();
    }

#pragma unroll
    for (int mt = 0; mt < 2; mt++)
#pragma unroll
        for (int nt = 0; nt < 4; nt++)
#pragma unroll
            for (int r = 0; r < 4; r++) {
                int row = bm + wm + mt * 16 + quad * 4 + r;
                int col = bn + wn + nt * 16 + l15;
                out[(size_t)row * CD + col] = acc[mt][nt][r] + bias[col];
            }
}

// ---------------------------------------------------------------------------
// Flash attention v4: round-2 LDS-staged structure + register prefetch +
// qt-major packing + exp2 softmax + MFMA row-sum.
// Q/K: bf16 [bh][S][64] (Q pre-scaled by QSC). V: bf16 [bh][64][S].
// 1D grid of 2048 blocks: qt = 31-(bx>>6) (big tiles dispatched first),
// bh = bx&63. Block: 256 thr (4 waves) = 64 query rows; K-tiles of 64.
// Per iter: [barrier; regs->LDS; barrier; issue next tile's global loads;
// compute] — loads for kt+1 fly during compute of kt.
// ---------------------------------------------------------------------------
__global__ __launch_bounds__(256) void attn_kernel(
    const bf16* __restrict__ Q, const bf16* __restrict__ Kg,
    const bf16* __restrict__ Vg, bf16* __restrict__ Ob) {
    __shared__ bf16 Ks[64 * 72];      // [key][dim]
    __shared__ bf16 Vt[64 * 72];      // [dim][key]
    __shared__ bf16 Ps[4][16 * 72];   // per-wave P tile [qrow][key]

    const int t = threadIdx.x;
    const int wave = t >> 6, lane = t & 63;
    const int quad = lane >> 4, l15 = lane & 15;
    const int qt = 31 - (blockIdx.x >> 6);   // qt-major, big first
    const int bh = blockIdx.x & 63;
    const int q0 = qt * 64;
    const int myRow0 = q0 + wave * 16;

    const bf16* Qh = Q + (size_t)bh * CS * 64;
    const bf16* Kh = Kg + (size_t)bh * CS * 64;
    const bf16* Vh = Vg + (size_t)bh * 64 * CS;

    // staging map: thread covers 16B x2 of the K tile row and V^T tile row
    const int strow = t >> 2, soff = (t & 3) * 16;
    const bf16* ksrc = Kh + (size_t)strow * 64 + soff;   // + kt*64*64
    const bf16* vsrc = Vh + (size_t)strow * CS + soff;   // + kt*64

    // ---- prefetch tile 0 into registers
    bf16x8 kr0 = *(const bf16x8*)ksrc;
    bf16x8 kr1 = *(const bf16x8*)(ksrc + 8);
    bf16x8 vr0 = *(const bf16x8*)vsrc;
    bf16x8 vr1 = *(const bf16x8*)(vsrc + 8);

    // ---- Q fragments (A-operand) straight from global, once
    const bf16* qsrc = Qh + (size_t)(myRow0 + l15) * 64 + quad * 8;
    bf16x8 qf0 = *(const bf16x8*)qsrc;
    bf16x8 qf1 = *(const bf16x8*)(qsrc + 32);

    floatx4 o[4] = {};
    float m_r[4], l_r[4];
#pragma unroll
    for (int r = 0; r < 4; r++) { m_r[r] = NEG_INF; l_r[r] = 0.f; }

    bf16x8 ones;
#pragma unroll
    for (int j = 0; j < 8; j++) ones[j] = (bf16)1.0f;

    bf16* ps = Ps[wave];

    for (int kt = 0; kt <= qt; kt++) {
        const int ks0 = kt * 64;
        __syncthreads();   // all waves done reading previous tile
        *(bf16x8*)&Ks[strow * 72 + soff]     = kr0;
        *(bf16x8*)&Ks[strow * 72 + soff + 8] = kr1;
        *(bf16x8*)&Vt[strow * 72 + soff]     = vr0;
        *(bf16x8*)&Vt[strow * 72 + soff + 8] = vr1;
        __syncthreads();
        // ---- issue next tile's loads now; latency hidden behind compute
        if (kt < qt) {
            const bf16* kn = ksrc + (size_t)(kt + 1) * 64 * 64;
            const bf16* vn = vsrc + (kt + 1) * 64;
            kr0 = *(const bf16x8*)kn;
            kr1 = *(const bf16x8*)(kn + 8);
            vr0 = *(const bf16x8*)vn;
            vr1 = *(const bf16x8*)(vn + 8);
        }
        // ---- QK^T: 4 key sub-tiles x 2 k-steps
        floatx4 sc[4] = {};
#pragma unroll
        for (int nt = 0; nt < 4; nt++) {
            bf16x8 kf0 = *(const bf16x8*)&Ks[(nt * 16 + l15) * 72 + quad * 8];
            bf16x8 kf1 = *(const bf16x8*)&Ks[(nt * 16 + l15) * 72 + 32 + quad * 8];
            sc[nt] = MFMA_16x16x32(qf0, kf0, sc[nt]);
            sc[nt] = MFMA_16x16x32(qf1, kf1, sc[nt]);
        }
        // ---- causal mask (diagonal tile only)
        if (ks0 + 63 > myRow0) {
#pragma unroll
            for (int nt = 0; nt < 4; nt++)
#pragma unroll
                for (int r = 0; r < 4; r++) {
                    int qrow = myRow0 + quad * 4 + r;
                    int kcol = ks0 + nt * 16 + l15;
                    if (kcol > qrow) sc[nt][r] = NEG_INF;
                }
        }
        // ---- running max + alpha (base-2 domain)
        float alpha[4];
#pragma unroll
        for (int r = 0; r < 4; r++) {
            float v = fmaxf(fmaxf(sc[0][r], sc[1][r]), fmaxf(sc[2][r], sc[3][r]));
#pragma unroll
            for (int off = 1; off < 16; off <<= 1) v = fmaxf(v, __shfl_xor(v, off));
            float mn = fmaxf(m_r[r], v);
            alpha[r] = __builtin_amdgcn_exp2f(m_r[r] - mn);
            m_r[r] = mn;
        }
#pragma unroll
        for (int nt = 0; nt < 4; nt++)
#pragma unroll
            for (int r = 0; r < 4; r++)
                sc[nt][r] = __builtin_amdgcn_exp2f(sc[nt][r] - m_r[r]);
        // ---- P: C-layout -> LDS -> A-layout (per-wave, no barrier needed)
#pragma unroll
        for (int nt = 0; nt < 4; nt++)
#pragma unroll
            for (int r = 0; r < 4; r++)
                ps[(quad * 4 + r) * 72 + nt * 16 + l15] = (bf16)sc[nt][r];
        bf16x8 pf0 = *(const bf16x8*)&ps[l15 * 72 + quad * 8];
        bf16x8 pf1 = *(const bf16x8*)&ps[l15 * 72 + 32 + quad * 8];
        // ---- row sums via MFMA against ones
        floatx4 sr = {};
        sr = MFMA_16x16x32(pf0, ones, sr);
        sr = MFMA_16x16x32(pf1, ones, sr);
        // ---- rescale o, update l, accumulate PV
#pragma unroll
        for (int dt = 0; dt < 4; dt++)
#pragma unroll
            for (int r = 0; r < 4; r++) o[dt][r] *= alpha[r];
#pragma unroll
        for (int r = 0; r < 4; r++) l_r[r] = l_r[r] * alpha[r] + sr[r];
#pragma unroll
        for (int dt = 0; dt < 4; dt++) {
            bf16x8 vf0 = *(const bf16x8*)&Vt[(dt * 16 + l15) * 72 + quad * 8];
            bf16x8 vf1 = *(const bf16x8*)&Vt[(dt * 16 + l15) * 72 + 32 + quad * 8];
            o[dt] = MFMA_16x16x32(pf0, vf0, o[dt]);
            o[dt] = MFMA_16x16x32(pf1, vf1, o[dt]);
        }
    }

    // ---- epilogue: normalize, store [B][S][H*64]
    const int b = bh >> 4, h = bh & 15;
    float rl[4];
#pragma unroll
    for (int r = 0; r < 4; r++) rl[r] = 1.f / l_r[r];
#pragma unroll
    for (int dt = 0; dt < 4; dt++)
#pragma unroll
        for (int r = 0; r < 4; r++) {
            int orow = q0 + wave * 16 + quad * 4 + r;
            int col = h * 64 + dt * 16 + l15;
            Ob[((size_t)b * CS + orow) * CD + col] = (bf16)(o[dt][r] * rl[r]);
        }
}

// ---------------------------------------------------------------------------
extern "C" void kernel_launch(void* const* d_in, const int* in_sizes, int n_in,
                              void* d_out, int out_size, void* d_ws, size_t ws_size,
                              hipStream_t stream) {
    const float* x  = (const float*)d_in[0];
    const float* Wq = (const float*)d_in[1];
    const float* bq = (const float*)d_in[2];
    const float* Wk = (const float*)d_in[3];
    const float* bk = (const float*)d_in[4];
    const float* Wv = (const float*)d_in[5];
    const float* bv = (const float*)d_in[6];
    const float* Wo = (const float*)d_in[7];
    const float* bo = (const float*)d_in[8];
    float* out = (float*)d_out;

    // workspace (bf16 elems): xb[4M] Wt[4*1M] Qb[4M] Kb[4M] Vb[4M] Ob[4M]
    bf16* xb = (bf16*)d_ws;
    bf16* Wt = xb + (size_t)CM * CD;
    bf16* Qb = Wt + (size_t)4 * CD * CD;
    bf16* Kb = Qb + (size_t)CB * CH * CS * 64;
    bf16* Vb = Kb + (size_t)CB * CH * CS * 64;
    bf16* Ob = Vb + (size_t)CB * CH * CS * 64;

    conv_x<<<(CM * CD) / (256 * 8), 256, 0, stream>>>(x, xb);
    conv_wt<<<dim3(CD / 64, CD / 64, 4), 256, 0, stream>>>(Wq, Wk, Wv, Wo, Wt);

    gemm_qkv<<<dim3(24, CM / 128), 256, 0, stream>>>(
        xb, Wt, bq, bk, bv, Qb, Kb, Vb);

    attn_kernel<<<2048, 256, 0, stream>>>(Qb, Kb, Vb, Ob);

    gemm_o<<<dim3(8, CM / 64), 256, 0, stream>>>(
        Ob, Wt + (size_t)3 * CD * CD, bo, out);
}

// Round 5
// 194.379 us; speedup vs baseline: 1.9016x; 1.1797x over previous
//
#include <hip/hip_runtime.h>
#include <hip/hip_bf16.h>

typedef __bf16 bf16;
typedef __bf16 bf16x4 __attribute__((ext_vector_type(4)));
typedef __bf16 bf16x8 __attribute__((ext_vector_type(8)));
typedef float floatx4 __attribute__((ext_vector_type(4)));

#define MFMA_16x16x32(a, b, c) __builtin_amdgcn_mfma_f32_16x16x32_bf16((a), (b), (c), 0, 0, 0)
#define NEG_INF (-__builtin_inff())

// Problem constants (B=2, S=2048, D=1024, H=16, d=64)
#define CB 2
#define CS 2048
#define CD 1024
#define CH 16
#define CM (CB * CS)
// Q prescale: DIM^-0.5 * log2(e)  (softmax done in base-2 domain)
#define QSC (0.03125f * 1.44269504088896340736f)

// async global->LDS, 16B per lane; LDS dest = wave-uniform base + lane*16
__device__ __forceinline__ void async16(const bf16* g, bf16* l) {
    __builtin_amdgcn_global_load_lds(
        (const __attribute__((address_space(1))) void*)g,
        (__attribute__((address_space(3))) void*)l, 16, 0, 0);
}

// ---------------------------------------------------------------------------
// Prep: x fp32 -> bf16
// ---------------------------------------------------------------------------
__global__ __launch_bounds__(256) void conv_x(const float* __restrict__ x,
                                              bf16* __restrict__ xb) {
    size_t i = ((size_t)blockIdx.x * 256 + threadIdx.x) * 8;
    float4 a = *(const float4*)(x + i);
    float4 b = *(const float4*)(x + i + 4);
    bf16x8 v;
    v[0] = (bf16)a.x; v[1] = (bf16)a.y; v[2] = (bf16)a.z; v[3] = (bf16)a.w;
    v[4] = (bf16)b.x; v[5] = (bf16)b.y; v[6] = (bf16)b.z; v[7] = (bf16)b.w;
    *(bf16x8*)(xb + i) = v;
}

// ---------------------------------------------------------------------------
// Prep: W [K][N] fp32 -> Wt [N][K] bf16 (64x64 LDS tile transpose)
// grid: (N/64, K/64, 4)  — z selects which W
// ---------------------------------------------------------------------------
__global__ __launch_bounds__(256) void conv_wt(
    const float* __restrict__ W0, const float* __restrict__ W1,
    const float* __restrict__ W2, const float* __restrict__ W3,
    bf16* __restrict__ Wt) {
    __shared__ bf16 Ws[64 * 68];
    const float* W = blockIdx.z == 0 ? W0 : blockIdx.z == 1 ? W1
                   : blockIdx.z == 2 ? W2 : W3;
    bf16* out = Wt + (size_t)blockIdx.z * CD * CD;
    const int t = threadIdx.x;
    const int n0 = blockIdx.x * 64, k0 = blockIdx.y * 64;
    const int rr = t >> 4, c4 = (t & 15) * 4;
#pragma unroll
    for (int i = 0; i < 4; i++) {
        int r = rr + i * 16;
        float4 f = *(const float4*)(W + (size_t)(k0 + r) * CD + n0 + c4);
        bf16x4 v;
        v[0] = (bf16)f.x; v[1] = (bf16)f.y; v[2] = (bf16)f.z; v[3] = (bf16)f.w;
        *(bf16x4*)&Ws[r * 68 + c4] = v;
    }
    __syncthreads();
#pragma unroll
    for (int i = 0; i < 4; i++) {
        int n = rr + i * 16;
        bf16x4 v;
#pragma unroll
        for (int j = 0; j < 4; j++) v[j] = Ws[(c4 + j) * 68 + n];
        *(bf16x4*)(out + (size_t)(n0 + n) * CD + k0 + c4) = v;
    }
}

// ---------------------------------------------------------------------------
// Fused QKV GEMM (m97 structure): 128x128 tile, BK=32, global_load_lds x16B.
// which = blockIdx.x>>3: 0->Q (scaled by QSC, [bh][S][64]), 1->K ([bh][S][64]),
// 2->V (transposed store [bh][64][S], packed bf16x4 along tokens).
// ---------------------------------------------------------------------------
__global__ __launch_bounds__(256) void gemm_qkv(
    const bf16* __restrict__ A, const bf16* __restrict__ Bt,
    const float* __restrict__ bq, const float* __restrict__ bk,
    const float* __restrict__ bv,
    bf16* __restrict__ Qb, bf16* __restrict__ Kb, bf16* __restrict__ Vb) {
    __shared__ bf16 As[128 * 32];
    __shared__ bf16 Bs[128 * 32];
    const int t = threadIdx.x, w = t >> 6, lane = t & 63;
    const int quad = lane >> 4, l15 = lane & 15;
    const int which = blockIdx.x >> 3;
    const int bn = (blockIdx.x & 7) * 128, bm = blockIdx.y * 128;
    const bf16* Bw = Bt + (size_t)which * CD * CD;

    const bf16* ag = A + (size_t)(bm + w * 16 + (lane >> 2)) * CD + (lane & 3) * 8;
    const bf16* bg = Bw + (size_t)(bn + w * 16 + (lane >> 2)) * CD + (lane & 3) * 8;
    const int lo = w * 16 * 32;   // wave-uniform LDS chunk base

    const int wm = (w >> 1) * 64, wn = (w & 1) * 64;
    floatx4 acc[4][4] = {};

    for (int k0 = 0; k0 < CD; k0 += 32) {
        async16(ag + k0, &As[lo]);
        async16(ag + (size_t)64 * CD + k0, &As[lo + 64 * 32]);
        async16(bg + k0, &Bs[lo]);
        async16(bg + (size_t)64 * CD + k0, &Bs[lo + 64 * 32]);
        __syncthreads();
        bf16x8 af[4], bfr[4];
#pragma unroll
        for (int mt = 0; mt < 4; mt++)
            af[mt] = *(const bf16x8*)&As[(wm + mt * 16 + l15) * 32 + quad * 8];
#pragma unroll
        for (int nt = 0; nt < 4; nt++)
            bfr[nt] = *(const bf16x8*)&Bs[(wn + nt * 16 + l15) * 32 + quad * 8];
#pragma unroll
        for (int mt = 0; mt < 4; mt++)
#pragma unroll
            for (int nt = 0; nt < 4; nt++)
                acc[mt][nt] = MFMA_16x16x32(af[mt], bfr[nt], acc[mt][nt]);
        __syncthreads();
    }

    const float* bias = which == 0 ? bq : which == 1 ? bk : bv;
    bf16* out = which == 0 ? Qb : Kb;
#pragma unroll
    for (int mt = 0; mt < 4; mt++) {
#pragma unroll
        for (int nt = 0; nt < 4; nt++) {
            int token = bm + wm + mt * 16 + quad * 4;      // 4 consecutive tokens
            int col = bn + wn + nt * 16 + l15;             // feature
            int b = token >> 11, s = token & (CS - 1);
            int h = col >> 6, dd = col & 63;
            if (which == 2) {
                // V^T [bh][d][S]: 4 tokens contiguous -> packed 8B store
                bf16x4 pv;
#pragma unroll
                for (int r = 0; r < 4; r++) pv[r] = (bf16)(acc[mt][nt][r] + bias[col]);
                *(bf16x4*)&Vb[(((size_t)(b * CH + h)) * 64 + dd) * CS + s] = pv;
            } else {
#pragma unroll
                for (int r = 0; r < 4; r++) {
                    float v = acc[mt][nt][r] + bias[col];
                    if (which == 0) v *= QSC;
                    out[(((size_t)(b * CH + h)) * CS + s + r) * 64 + dd] = (bf16)v;
                }
            }
        }
    }
}

// ---------------------------------------------------------------------------
// O-projection GEMM: 64x128 tile, fp32 output. grid: (8, M/64).
// ---------------------------------------------------------------------------
__global__ __launch_bounds__(256) void gemm_o(
    const bf16* __restrict__ A, const bf16* __restrict__ Bt,
    const float* __restrict__ bias, float* __restrict__ out) {
    __shared__ bf16 As[64 * 32];
    __shared__ bf16 Bs[128 * 32];
    const int t = threadIdx.x, w = t >> 6, lane = t & 63;
    const int quad = lane >> 4, l15 = lane & 15;
    const int bn = blockIdx.x * 128, bm = blockIdx.y * 64;

    const bf16* ag = A + (size_t)(bm + w * 16 + (lane >> 2)) * CD + (lane & 3) * 8;
    const bf16* bg = Bt + (size_t)(bn + w * 16 + (lane >> 2)) * CD + (lane & 3) * 8;
    const int lo = w * 16 * 32;

    const int wm = (w >> 1) * 32, wn = (w & 1) * 64;
    floatx4 acc[2][4] = {};

    for (int k0 = 0; k0 < CD; k0 += 32) {
        async16(ag + k0, &As[lo]);
        async16(bg + k0, &Bs[lo]);
        async16(bg + (size_t)64 * CD + k0, &Bs[lo + 64 * 32]);
        __syncthreads();
        bf16x8 af[2], bfr[4];
#pragma unroll
        for (int mt = 0; mt < 2; mt++)
            af[mt] = *(const bf16x8*)&As[(wm + mt * 16 + l15) * 32 + quad * 8];
#pragma unroll
        for (int nt = 0; nt < 4; nt++)
            bfr[nt] = *(const bf16x8*)&Bs[(wn + nt * 16 + l15) * 32 + quad * 8];
#pragma unroll
        for (int mt = 0; mt < 2; mt++)
#pragma unroll
            for (int nt = 0; nt < 4; nt++)
                acc[mt][nt] = MFMA_16x16x32(af[mt], bfr[nt], acc[mt][nt]);
        __syncthreads();
    }

#pragma unroll
    for (int mt = 0; mt < 2; mt++)
#pragma unroll
        for (int nt = 0; nt < 4; nt++)
#pragma unroll
            for (int r = 0; r < 4; r++) {
                int row = bm + wm + mt * 16 + quad * 4 + r;
                int col = bn + wn + nt * 16 + l15;
                out[(size_t)row * CD + col] = acc[mt][nt][r] + bias[col];
            }
}

// ---------------------------------------------------------------------------
// Flash attention v5 — TRANSPOSED score scheme + 32 qrows/wave.
// Computes S^T = K·Q^T (A=K-frag, B=Q-frag) so qrow = lane (l15):
//   - row stats (m,l,alpha) are per-lane scalars: 2 shuffles per reduction
//   - P^T store = 8 packed ds_write_b64; P^T B-frag read = 4 ds_read_b128
//   - O^T = V^T·P^T; epilogue packs bf16x4 stores
// Each wave owns 32 qrows (2 groups g) -> every K/V LDS fragment feeds 2
// MFMAs (A-side reuse), halving the DS-pipe load per FLOP vs v4.
// Block = 256 thr = 128 qrows; 64-key tiles; K/V prefetched into registers.
// Grid 512 = 32 bh x 16 q-blocks; first 256 blocks = long halves (qb 15..8),
// next 256 = short (qb 0..7) so round-robin placement pairs long+short per CU.
// ---------------------------------------------------------------------------
__global__ __launch_bounds__(256) void attn_kernel(
    const bf16* __restrict__ Q, const bf16* __restrict__ Kg,
    const bf16* __restrict__ Vg, bf16* __restrict__ Ob) {
    __shared__ bf16 Ks[64 * 72];      // [key][dim]
    __shared__ bf16 Vt[64 * 72];      // [dim][key]
    __shared__ bf16 Pt[4][32 * 72];   // per-wave P^T as [qrow][key]

    const int t = threadIdx.x;
    const int w = t >> 6, lane = t & 63;
    const int quad = lane >> 4, l15 = lane & 15;

    const int half = blockIdx.x >> 8;        // 0: long q-blocks, 1: short
    const int slot = blockIdx.x & 255;
    const int bh   = slot & 31;              // B*H = 32
    const int qq   = slot >> 5;              // 0..7
    const int qb   = half ? qq : (15 - qq);  // q-block (128 rows) 0..15
    const int q0   = qb * 128;
    const int wrow0 = q0 + w * 32;           // this wave's first qrow
    const int nT = 2 * qb + 2;               // 64-key tiles to process

    const bf16* Qh = Q + (size_t)bh * CS * 64;
    const bf16* Kh = Kg + (size_t)bh * CS * 64;
    const bf16* Vh = Vg + (size_t)bh * 64 * CS;

    // staging map: thread covers 16B x2 of one K row and one V^T row
    const int strow = t >> 2, soff = (t & 3) * 16;
    const bf16* ksrc = Kh + (size_t)strow * 64 + soff;   // + kt*64*64
    const bf16* vsrc = Vh + (size_t)strow * CS + soff;   // + kt*64

    // ---- prefetch tile 0 into registers
    bf16x8 kr0 = *(const bf16x8*)ksrc;
    bf16x8 kr1 = *(const bf16x8*)(ksrc + 8);
    bf16x8 vr0 = *(const bf16x8*)vsrc;
    bf16x8 vr1 = *(const bf16x8*)(vsrc + 8);

    // ---- Q fragments (B-operand of S^T): Q[qrow=g*16+l15][dim=quad*8+j+32c]
    bf16x8 qf[2][2];
#pragma unroll
    for (int g = 0; g < 2; g++) {
        const bf16* qsrc = Qh + (size_t)(wrow0 + g * 16 + l15) * 64 + quad * 8;
        qf[g][0] = *(const bf16x8*)qsrc;
        qf[g][1] = *(const bf16x8*)(qsrc + 32);
    }

    floatx4 o[4][2] = {};        // O^T: [dim-subtile][qrow-group]
    float m_r[2] = {NEG_INF, NEG_INF}, l_r[2] = {0.f, 0.f};

    bf16* pw = Pt[w];

    for (int kt = 0; kt < nT; kt++) {
        const int ks0 = kt * 64;
        __syncthreads();   // all waves done reading previous tile
        *(bf16x8*)&Ks[strow * 72 + soff]     = kr0;
        *(bf16x8*)&Ks[strow * 72 + soff + 8] = kr1;
        *(bf16x8*)&Vt[strow * 72 + soff]     = vr0;
        *(bf16x8*)&Vt[strow * 72 + soff + 8] = vr1;
        __syncthreads();
        // ---- issue next tile's global loads (dummy tile 0 on last iter)
        {
            int nk = (kt + 1 < nT) ? kt + 1 : 0;
            const bf16* kn = ksrc + (size_t)nk * 64 * 64;
            const bf16* vn = vsrc + nk * 64;
            kr0 = *(const bf16x8*)kn;
            kr1 = *(const bf16x8*)(kn + 8);
            vr0 = *(const bf16x8*)vn;
            vr1 = *(const bf16x8*)(vn + 8);
        }
        // waves whose rows are all below this key tile skip compute
        if (ks0 > wrow0 + 31) continue;

        // ---- S^T = K·Q^T: lane holds S^T[key=nt*16+quad*4+r][qrow=g*16+l15]
        floatx4 sc[2][4] = {};
#pragma unroll
        for (int nt = 0; nt < 4; nt++) {
            bf16x8 af0 = *(const bf16x8*)&Ks[(nt * 16 + l15) * 72 + quad * 8];
            bf16x8 af1 = *(const bf16x8*)&Ks[(nt * 16 + l15) * 72 + 32 + quad * 8];
#pragma unroll
            for (int g = 0; g < 2; g++) {
                sc[g][nt] = MFMA_16x16x32(af0, qf[g][0], sc[g][nt]);
                sc[g][nt] = MFMA_16x16x32(af1, qf[g][1], sc[g][nt]);
            }
        }
        // ---- causal mask (tiles overlapping the wave's diagonal band)
        if (ks0 + 63 > wrow0) {
#pragma unroll
            for (int g = 0; g < 2; g++) {
                int qrow = wrow0 + g * 16 + l15;
#pragma unroll
                for (int nt = 0; nt < 4; nt++)
#pragma unroll
                    for (int r = 0; r < 4; r++)
                        if (ks0 + nt * 16 + quad * 4 + r > qrow)
                            sc[g][nt][r] = NEG_INF;
            }
        }
        // ---- online softmax per qrow-group: per-lane stats, 2 shuffles
        float alpha_g[2];
#pragma unroll
        for (int g = 0; g < 2; g++) {
            float mx = NEG_INF;
#pragma unroll
            for (int nt = 0; nt < 4; nt++)
#pragma unroll
                for (int r = 0; r < 4; r++) mx = fmaxf(mx, sc[g][nt][r]);
            mx = fmaxf(mx, __shfl_xor(mx, 16));
            mx = fmaxf(mx, __shfl_xor(mx, 32));
            float mn = fmaxf(m_r[g], mx);
            alpha_g[g] = __builtin_amdgcn_exp2f(m_r[g] - mn);
            m_r[g] = mn;
            float sum = 0.f;
#pragma unroll
            for (int nt = 0; nt < 4; nt++)
#pragma unroll
                for (int r = 0; r < 4; r++) {
                    sc[g][nt][r] = __builtin_amdgcn_exp2f(sc[g][nt][r] - mn);
                    sum += sc[g][nt][r];
                }
            sum += __shfl_xor(sum, 16);
            sum += __shfl_xor(sum, 32);
            l_r[g] = l_r[g] * alpha_g[g] + sum;
        }
        // ---- P^T -> LDS: packed 8B writes ([qrow][key], keys quad*4+r contig)
#pragma unroll
        for (int g = 0; g < 2; g++)
#pragma unroll
            for (int nt = 0; nt < 4; nt++) {
                bf16x4 pk;
#pragma unroll
                for (int r = 0; r < 4; r++) pk[r] = (bf16)sc[g][nt][r];
                *(bf16x4*)&pw[(g * 16 + l15) * 72 + nt * 16 + quad * 4] = pk;
            }
        // ---- P^T B-frags: B[k=key=quad*8+j+32c][n=qrow=l15]
        bf16x8 bp[2][2];
#pragma unroll
        for (int g = 0; g < 2; g++) {
            bp[g][0] = *(const bf16x8*)&pw[(g * 16 + l15) * 72 + quad * 8];
            bp[g][1] = *(const bf16x8*)&pw[(g * 16 + l15) * 72 + 32 + quad * 8];
        }
        // ---- rescale O^T by per-lane alpha, then accumulate V^T·P^T
#pragma unroll
        for (int dt = 0; dt < 4; dt++)
#pragma unroll
            for (int g = 0; g < 2; g++)
#pragma unroll
                for (int r = 0; r < 4; r++) o[dt][g][r] *= alpha_g[g];
#pragma unroll
        for (int dt = 0; dt < 4; dt++) {
            bf16x8 av0 = *(const bf16x8*)&Vt[(dt * 16 + l15) * 72 + quad * 8];
            bf16x8 av1 = *(const bf16x8*)&Vt[(dt * 16 + l15) * 72 + 32 + quad * 8];
#pragma unroll
            for (int g = 0; g < 2; g++) {
                o[dt][g] = MFMA_16x16x32(av0, bp[g][0], o[dt][g]);
                o[dt][g] = MFMA_16x16x32(av1, bp[g][1], o[dt][g]);
            }
        }
    }

    // ---- epilogue: O^T lane layout: qrow=g*16+l15, dim=dt*16+quad*4+r
    const int b = bh >> 4, h = bh & 15;
#pragma unroll
    for (int g = 0; g < 2; g++) {
        float rl = 1.f / l_r[g];
        int row = wrow0 + g * 16 + l15;
#pragma unroll
        for (int dt = 0; dt < 4; dt++) {
            bf16x4 ov;
#pragma unroll
            for (int r = 0; r < 4; r++) ov[r] = (bf16)(o[dt][g][r] * rl);
            *(bf16x4*)&Ob[((size_t)b * CS + row) * CD + h * 64 + dt * 16 + quad * 4] = ov;
        }
    }
}

// ---------------------------------------------------------------------------
extern "C" void kernel_launch(void* const* d_in, const int* in_sizes, int n_in,
                              void* d_out, int out_size, void* d_ws, size_t ws_size,
                              hipStream_t stream) {
    const float* x  = (const float*)d_in[0];
    const float* Wq = (const float*)d_in[1];
    const float* bq = (const float*)d_in[2];
    const float* Wk = (const float*)d_in[3];
    const float* bk = (const float*)d_in[4];
    const float* Wv = (const float*)d_in[5];
    const float* bv = (const float*)d_in[6];
    const float* Wo = (const float*)d_in[7];
    const float* bo = (const float*)d_in[8];
    float* out = (float*)d_out;

    // workspace (bf16 elems): xb[4M] Wt[4*1M] Qb[4M] Kb[4M] Vb[4M] Ob[4M]
    bf16* xb = (bf16*)d_ws;
    bf16* Wt = xb + (size_t)CM * CD;
    bf16* Qb = Wt + (size_t)4 * CD * CD;
    bf16* Kb = Qb + (size_t)CB * CH * CS * 64;
    bf16* Vb = Kb + (size_t)CB * CH * CS * 64;
    bf16* Ob = Vb + (size_t)CB * CH * CS * 64;

    conv_x<<<(CM * CD) / (256 * 8), 256, 0, stream>>>(x, xb);
    conv_wt<<<dim3(CD / 64, CD / 64, 4), 256, 0, stream>>>(Wq, Wk, Wv, Wo, Wt);

    gemm_qkv<<<dim3(24, CM / 128), 256, 0, stream>>>(
        xb, Wt, bq, bk, bv, Qb, Kb, Vb);

    // 512 blocks = 32 bh x 16 q-blocks (128 rows each), long halves first
    attn_kernel<<<512, 256, 0, stream>>>(Qb, Kb, Vb, Ob);

    gemm_o<<<dim3(8, CM / 64), 256, 0, stream>>>(
        Ob, Wt + (size_t)3 * CD * CD, bo, out);
}